// Round 1
// baseline (258.560 us; speedup 1.0000x reference)
//
#include <hip/hip_runtime.h>

// LSTM: T=512, B=4096, IN=1, H=12.
// Design: 1 thread per (cell, j); thread owns W_hh rows {j, 12+j, 24+j, 36+j}
// in 48 VGPRs; 5 cells packed per wave (60/64 lanes); block = 1 wave so
// __syncthreads is single-wave-cheap. h exchanged per step through a
// double-buffered LDS buffer (1 ds_write + 3 ds_read_b128 broadcasts).
// X staged into LDS in 64-step chunks to amortize global latency.
// fc output dot computed redundantly from the gathered h, lagged one step.

#define TT    512
#define NB    4096
#define HH    12
#define CPB   5      // cells per block (one wave, 60 active lanes)
#define CHUNK 64     // X staging chunk; TT % CHUNK == 0
#define HPAD  20     // padded h row (floats): 16B-aligned, banks spread

__device__ __forceinline__ float sigm(float x) {
    // 1 / (1 + 2^(-x*log2e))
    return __builtin_amdgcn_rcpf(1.0f + __builtin_amdgcn_exp2f(-1.4426950408889634f * x));
}
__device__ __forceinline__ float tanh_fast(float x) {
    // 1 - 2/(2^(x*2*log2e) + 1)
    return 1.0f - 2.0f * __builtin_amdgcn_rcpf(1.0f + __builtin_amdgcn_exp2f(2.8853900817779268f * x));
}

__global__ __launch_bounds__(64)
void lstm_fused(const float* __restrict__ X,
                const float* __restrict__ W_ih,
                const float* __restrict__ W_hh,
                const float* __restrict__ b_ih,
                const float* __restrict__ b_hh,
                const float* __restrict__ fc_w,
                const float* __restrict__ fc_b,
                float* __restrict__ out)
{
    __shared__ float hbuf[2][CPB][HPAD];
    __shared__ float xchunk[CHUNK][CPB];

    const int lane = threadIdx.x;           // 0..63
    const int c0   = lane / HH;             // 0..4 valid, 5 for idle lanes
    const int j    = lane - c0 * HH;        // 0..11
    const int cs   = (c0 > CPB - 1) ? 0 : c0;  // clamp for LDS safety
    const int cellbase = blockIdx.x * CPB;
    const int cell = cellbase + cs;
    const bool active = (lane < CPB * HH) && (cell < NB);

    // zero both h buffers (state h0 = 0)
    for (int idx = lane; idx < 2 * CPB * HPAD; idx += 64)
        ((float*)hbuf)[idx] = 0.0f;

    // per-thread recurrent weights: rows j, 12+j, 24+j, 36+j of W_hh [48][12]
    float wi[HH], wf[HH], wg[HH], wo[HH], fcw[HH];
    #pragma unroll
    for (int k = 0; k < HH; ++k) {
        wi[k] = W_hh[(0 * HH + j) * HH + k];
        wf[k] = W_hh[(1 * HH + j) * HH + k];
        wg[k] = W_hh[(2 * HH + j) * HH + k];
        wo[k] = W_hh[(3 * HH + j) * HH + k];
        fcw[k] = fc_w[k];
    }
    const float bi  = b_ih[0 * HH + j] + b_hh[0 * HH + j];
    const float bf  = b_ih[1 * HH + j] + b_hh[1 * HH + j];
    const float bg  = b_ih[2 * HH + j] + b_hh[2 * HH + j];
    const float bo  = b_ih[3 * HH + j] + b_hh[3 * HH + j];
    const float wxi = W_ih[0 * HH + j];   // IN == 1, so W_ih is flat [48]
    const float wxf = W_ih[1 * HH + j];
    const float wxg = W_ih[2 * HH + j];
    const float wxo = W_ih[3 * HH + j];
    const float fcb = fc_b[0];

    float cst = 0.0f;   // cell state c[cell][j]

    for (int t = 0; t < TT; ++t) {
        // stage X[t .. t+CHUNK) for this block's cells into LDS
        if ((t & (CHUNK - 1)) == 0) {
            const int tt = t + lane;   // CHUNK == 64 == wave size
            #pragma unroll
            for (int k = 0; k < CPB; ++k) {
                const int cc = cellbase + k;
                xchunk[lane][k] = (cc < NB) ? X[tt * NB + cc] : 0.0f;
            }
        }
        __syncthreads();   // single-wave block: near-free; orders LDS

        // gather h (state after step t-1) — broadcast reads
        float hv[HH];
        {
            const float4 a = *(const float4*)&hbuf[t & 1][cs][0];
            const float4 b = *(const float4*)&hbuf[t & 1][cs][4];
            const float4 d = *(const float4*)&hbuf[t & 1][cs][8];
            hv[0] = a.x; hv[1] = a.y; hv[2]  = a.z; hv[3]  = a.w;
            hv[4] = b.x; hv[5] = b.y; hv[6]  = b.z; hv[7]  = b.w;
            hv[8] = d.x; hv[9] = d.y; hv[10] = d.z; hv[11] = d.w;
        }

        // output for step t-1 (h gathered now is h_{t-1})
        if (t > 0 && active && j == 0) {
            float acc = fcb;
            #pragma unroll
            for (int k = 0; k < HH; ++k) acc = fmaf(hv[k], fcw[k], acc);
            out[(t - 1) * NB + cell] = acc;
        }

        // gates: x-projection + recurrent dots (4 independent 12-FMA chains)
        const float xv = xchunk[t & (CHUNK - 1)][cs];
        float gi = fmaf(xv, wxi, bi);
        float gf = fmaf(xv, wxf, bf);
        float gg = fmaf(xv, wxg, bg);
        float go = fmaf(xv, wxo, bo);
        #pragma unroll
        for (int k = 0; k < HH; ++k) {
            gi = fmaf(wi[k], hv[k], gi);
            gf = fmaf(wf[k], hv[k], gf);
            gg = fmaf(wg[k], hv[k], gg);
            go = fmaf(wo[k], hv[k], go);
        }
        const float si = sigm(gi);
        const float sf = sigm(gf);
        const float tg = tanh_fast(gg);
        const float so = sigm(go);
        cst = fmaf(sf, cst, si * tg);
        const float hn = so * tanh_fast(cst);

        // publish h_t to the other buffer (idle lanes must not clobber row 0)
        if (lane < CPB * HH) hbuf[(t + 1) & 1][cs][j] = hn;
    }

    // final output for t = TT-1; state is in hbuf[TT & 1] == hbuf[0]
    __syncthreads();
    {
        const float4 a = *(const float4*)&hbuf[0][cs][0];
        const float4 b = *(const float4*)&hbuf[0][cs][4];
        const float4 d = *(const float4*)&hbuf[0][cs][8];
        if (active && j == 0) {
            float acc = fcb;
            acc = fmaf(a.x, fcw[0], acc);  acc = fmaf(a.y, fcw[1], acc);
            acc = fmaf(a.z, fcw[2], acc);  acc = fmaf(a.w, fcw[3], acc);
            acc = fmaf(b.x, fcw[4], acc);  acc = fmaf(b.y, fcw[5], acc);
            acc = fmaf(b.z, fcw[6], acc);  acc = fmaf(b.w, fcw[7], acc);
            acc = fmaf(d.x, fcw[8], acc);  acc = fmaf(d.y, fcw[9], acc);
            acc = fmaf(d.z, fcw[10], acc); acc = fmaf(d.w, fcw[11], acc);
            out[(TT - 1) * NB + cell] = acc;
        }
    }
}

extern "C" void kernel_launch(void* const* d_in, const int* in_sizes, int n_in,
                              void* d_out, int out_size, void* d_ws, size_t ws_size,
                              hipStream_t stream) {
    const float* X    = (const float*)d_in[0];
    const float* W_ih = (const float*)d_in[1];
    const float* W_hh = (const float*)d_in[2];
    const float* b_ih = (const float*)d_in[3];
    const float* b_hh = (const float*)d_in[4];
    const float* fc_w = (const float*)d_in[5];
    const float* fc_b = (const float*)d_in[6];
    float* out = (float*)d_out;

    const int grid = (NB + CPB - 1) / CPB;   // 820 blocks of 1 wave
    lstm_fused<<<grid, 64, 0, stream>>>(X, W_ih, W_hh, b_ih, b_hh, fc_w, fc_b, out);
}

// Round 2
// 240.129 us; speedup vs baseline: 1.0768x; 1.0768x over previous
//
#include <hip/hip_runtime.h>

// LSTM: T=512, B=4096, IN=1, H=12.
// R2: barrier-free single-wave blocks. 1 thread per (cell, j); thread owns
// W_hh rows {j,12+j,24+j,36+j} in 48 VGPRs; 5 cells/wave (60/64 lanes).
// h exchanged per step through a SINGLE LDS buffer using wave-synchronous
// ordering (DS unit processes a wave's ops in order; compiler inserts
// lgkmcnt waits) — no __syncthreads, so the per-step out-store is never
// drained (R1's __syncthreads forced s_waitcnt vmcnt(0) every step: ~600
// stall cyc/step). Gather is software-pipelined: write h_t then read next
// hv at loop bottom; initial hv=0 is free; final gather feeds last out-dot.

#define TT    512
#define NB    4096
#define HH    12
#define CPB   5      // cells per block (one wave, 60 active lanes)
#define CHUNK 64     // X staging chunk; TT % CHUNK == 0
#define HPAD  20     // padded h row (floats): 16B-aligned, banks spread

__device__ __forceinline__ float sigm(float x) {
    return __builtin_amdgcn_rcpf(1.0f + __builtin_amdgcn_exp2f(-1.4426950408889634f * x));
}
__device__ __forceinline__ float tanh_fast(float x) {
    return 1.0f - 2.0f * __builtin_amdgcn_rcpf(1.0f + __builtin_amdgcn_exp2f(2.8853900817779268f * x));
}

__global__ __launch_bounds__(64)
void lstm_fused(const float* __restrict__ X,
                const float* __restrict__ W_ih,
                const float* __restrict__ W_hh,
                const float* __restrict__ b_ih,
                const float* __restrict__ b_hh,
                const float* __restrict__ fc_w,
                const float* __restrict__ fc_b,
                float* __restrict__ out)
{
    __shared__ float hbuf[CPB][HPAD];
    __shared__ float xchunk[CHUNK][CPB];

    const int lane = threadIdx.x;            // 0..63
    const int c0   = lane / HH;              // 0..4 valid, 5 for idle lanes
    const int j    = lane - c0 * HH;         // 0..11
    const int cs   = (c0 > CPB - 1) ? 0 : c0;   // clamp for LDS safety
    const int cellbase = blockIdx.x * CPB;
    const int cell = cellbase + cs;
    const bool writer = (lane < CPB * HH);   // lanes allowed to write hbuf
    const bool active = writer && (cell < NB);
    const bool outlane = active && (j == 0);

    // per-thread recurrent weights: rows j, 12+j, 24+j, 36+j of W_hh [48][12]
    float wi[HH], wf[HH], wg[HH], wo[HH], fcw[HH];
    #pragma unroll
    for (int k = 0; k < HH; ++k) {
        wi[k] = W_hh[(0 * HH + j) * HH + k];
        wf[k] = W_hh[(1 * HH + j) * HH + k];
        wg[k] = W_hh[(2 * HH + j) * HH + k];
        wo[k] = W_hh[(3 * HH + j) * HH + k];
        fcw[k] = fc_w[k];
    }
    const float bi  = b_ih[0 * HH + j] + b_hh[0 * HH + j];
    const float bf  = b_ih[1 * HH + j] + b_hh[1 * HH + j];
    const float bg  = b_ih[2 * HH + j] + b_hh[2 * HH + j];
    const float bo  = b_ih[3 * HH + j] + b_hh[3 * HH + j];
    const float wxi = W_ih[0 * HH + j];   // IN == 1, W_ih flat [48]
    const float wxf = W_ih[1 * HH + j];
    const float wxg = W_ih[2 * HH + j];
    const float wxo = W_ih[3 * HH + j];
    const float fcb = fc_b[0];

    float cst = 0.0f;     // cell state c[cell][j]
    float hv[HH];         // gathered h of my cell (h_{t-1}); h0 = 0
    #pragma unroll
    for (int k = 0; k < HH; ++k) hv[k] = 0.0f;

    #pragma unroll 2
    for (int t = 0; t < TT; ++t) {
        // stage X[t .. t+CHUNK) for this block's cells into LDS
        if ((t & (CHUNK - 1)) == 0) {
            const int tt = t + lane;   // CHUNK == 64 == wave size
            #pragma unroll
            for (int k = 0; k < CPB; ++k) {
                const int cc = cellbase + k;
                xchunk[lane][k] = (cc < NB) ? X[tt * NB + cc] : 0.0f;
            }
        }

        // fc output for step t-1 (hv currently holds h_{t-1})
        if (t > 0 && outlane) {
            float acc = fcb;
            #pragma unroll
            for (int k = 0; k < HH; ++k) acc = fmaf(hv[k], fcw[k], acc);
            out[(t - 1) * NB + cell] = acc;
        }

        // gates: x-projection + recurrent dots (4 independent 12-FMA chains)
        const float xv = xchunk[t & (CHUNK - 1)][cs];
        float gi = fmaf(xv, wxi, bi);
        float gf = fmaf(xv, wxf, bf);
        float gg = fmaf(xv, wxg, bg);
        float go = fmaf(xv, wxo, bo);
        #pragma unroll
        for (int k = 0; k < HH; ++k) {
            gi = fmaf(wi[k], hv[k], gi);
            gf = fmaf(wf[k], hv[k], gf);
            gg = fmaf(wg[k], hv[k], gg);
            go = fmaf(wo[k], hv[k], go);
        }
        const float si = sigm(gi);
        const float sf = sigm(gf);
        const float tg = tanh_fast(gg);
        const float so = sigm(go);
        cst = fmaf(sf, cst, si * tg);
        const float hn = so * tanh_fast(cst);

        // publish h_t (idle lanes must not clobber row 0), then gather it.
        // Single wave: all lanes' ds_write issues before the ds_read; DS
        // ops are processed in order per wave, so the read sees h_t.
        if (writer) hbuf[cs][j] = hn;
        {
            const float4 a = *(const float4*)&hbuf[cs][0];
            const float4 b = *(const float4*)&hbuf[cs][4];
            const float4 d = *(const float4*)&hbuf[cs][8];
            hv[0] = a.x; hv[1] = a.y; hv[2]  = a.z; hv[3]  = a.w;
            hv[4] = b.x; hv[5] = b.y; hv[6]  = b.z; hv[7]  = b.w;
            hv[8] = d.x; hv[9] = d.y; hv[10] = d.z; hv[11] = d.w;
        }
    }

    // final output for t = TT-1 (hv now holds h_{TT-1})
    if (outlane) {
        float acc = fcb;
        #pragma unroll
        for (int k = 0; k < HH; ++k) acc = fmaf(hv[k], fcw[k], acc);
        out[(TT - 1) * NB + cell] = acc;
    }
}

extern "C" void kernel_launch(void* const* d_in, const int* in_sizes, int n_in,
                              void* d_out, int out_size, void* d_ws, size_t ws_size,
                              hipStream_t stream) {
    const float* X    = (const float*)d_in[0];
    const float* W_ih = (const float*)d_in[1];
    const float* W_hh = (const float*)d_in[2];
    const float* b_ih = (const float*)d_in[3];
    const float* b_hh = (const float*)d_in[4];
    const float* fc_w = (const float*)d_in[5];
    const float* fc_b = (const float*)d_in[6];
    float* out = (float*)d_out;

    const int grid = (NB + CPB - 1) / CPB;   // 820 blocks of 1 wave
    lstm_fused<<<grid, 64, 0, stream>>>(X, W_ih, W_hh, b_ih, b_hh, fc_w, fc_b, out);
}